// Round 11
// baseline (3847.203 us; speedup 1.0000x reference)
//
#include <hip/hip_runtime.h>
#include <math.h>

// B=32, L=1024, D=256, G=768
#define NROWS 32768  // B*L

typedef float v4 __attribute__((ext_vector_type(4)));
typedef _Float16 h2 __attribute__((ext_vector_type(2)));
typedef _Float16 f16x8 __attribute__((ext_vector_type(8)));
typedef float f32x4 __attribute__((ext_vector_type(4)));

__device__ __forceinline__ float geluf(float x){ return 0.5f*x*(1.0f+erff(x*0.70710678118654752f)); }
__device__ __forceinline__ float sigm(float x){ return 1.0f/(1.0f+expf(-x)); }

__device__ __forceinline__ float dot2(h2 a, h2 b, float c){
#if __has_builtin(__builtin_amdgcn_fdot2)
    return __builtin_amdgcn_fdot2(a, b, c, false);
#else
    return c + (float)a.x*(float)b.x + (float)a.y*(float)b.y;
#endif
}
__device__ __forceinline__ h2 cvt2(float2 a){ return h2{(_Float16)a.x, (_Float16)a.y}; }

// barrier that does NOT drain vmcnt: LDS visibility only. Global prefetch
// loads / output stores stay in flight across it.
__device__ __forceinline__ void wg_barrier(){
    asm volatile("s_waitcnt lgkmcnt(0)" ::: "memory");
    __builtin_amdgcn_s_barrier();
    __builtin_amdgcn_sched_barrier(0);
}

// ---------------- start embed: sh[b,d] ----------------
__global__ __launch_bounds__(256) void k_start_embed(
    const float* __restrict__ ne, const float* __restrict__ w0, const float* __restrict__ b0,
    const float* __restrict__ w1, const float* __restrict__ b1,
    const float* __restrict__ w2, const float* __restrict__ b2,
    float* __restrict__ sh)
{
    __shared__ __align__(16) float encL[1024];
    __shared__ __align__(16) float g1[256];
    __shared__ __align__(16) float g2[256];
    int b = blockIdx.x, t = threadIdx.x;
    for (int i = t; i < 1024; i += 256) encL[i] = ne[b*1024 + i];
    __syncthreads();
    const float4* wr = (const float4*)(w0 + (size_t)t*1024);
    const float4* e4 = (const float4*)encL;
    float a0=0,a1=0,a2=0,a3=0;
    #pragma unroll 8
    for (int k = 0; k < 256; ++k){ float4 w = wr[k], e = e4[k];
        a0 += w.x*e.x; a1 += w.y*e.y; a2 += w.z*e.z; a3 += w.w*e.w; }
    float t1 = a0+a1+a2+a3 + b0[t];
    float res = t1;
    g1[t] = geluf(t1);
    __syncthreads();
    const float4* w1r = (const float4*)(w1 + (size_t)t*256);
    const float4* g14 = (const float4*)g1;
    a0=a1=a2=a3=0.f;
    #pragma unroll 8
    for (int k = 0; k < 64; ++k){ float4 w = w1r[k], e = g14[k];
        a0 += w.x*e.x; a1 += w.y*e.y; a2 += w.z*e.z; a3 += w.w*e.w; }
    g2[t] = geluf(a0+a1+a2+a3 + b1[t]);
    __syncthreads();
    const float4* w2r = (const float4*)(w2 + (size_t)t*256);
    const float4* g24 = (const float4*)g2;
    a0=a1=a2=a3=0.f;
    #pragma unroll 8
    for (int k = 0; k < 64; ++k){ float4 w = w2r[k], e = g24[k];
        a0 += w.x*e.x; a1 += w.y*e.y; a2 += w.z*e.z; a3 += w.w*e.w; }
    sh[b*256 + t] = a0+a1+a2+a3 + b2[t] + res;
}

// permuted f16 index within an hbuf row for hidden dim:
// dim = (hi:2)(mid:3)(lo:3) -> idx = mid*32 + hi*8 + lo  (bijective).
// Float4 slot s = mid*4 + hi holds dims hi*64 + mid*8 .. +8. K-half reads
// become 2-address wave broadcasts (conflict-free); writes 2-way (free).
__device__ __forceinline__ int hperm(int dim){
    return ((dim >> 3) & 7)*32 + ((dim >> 6) << 3) + (dim & 7);
}

// ---------------- GRU scan v11: wR/wZ in regs, wN in LDS ----------------
// Grant model (R3-R10, 7 data points): VGPR grant = 65536 regs / WG threads,
// hard cap = full 256KB CU register file; attributes/LDS pads cannot raise it.
// f16 weights (384KB) can NEVER be fully register-resident -> place the
// overflow in LDS deliberately instead of compiler scratch-spill.
// 512 threads; thread (d = t>>1, half = t&1) owns gate rows d (r), d+256 (z),
// d+512 (n) over K-half [half*128, +128). Regs: wR+wZ halves = 128 h2 regs
// (+~25 state; ~25-reg residual spill, 4x less than v10's ~95). LDS: wN full
// 128KB as wNs[kk][t] float4 -> lane t reads consecutive 16B, conflict-free;
// 128 ds_read_b128/CU/step = 128KB @ 256B/clk ~= 512cy, overlaps VALU.
// LDS total ~133KB also forces 1 WG/CU. One lgkm-only barrier per step.
template<int LAYER>
__global__ __launch_bounds__(512) void k_gru3(
    const float* __restrict__ w_hh, const float* __restrict__ b_hh,
    const float* __restrict__ w_ih0, const float* __restrict__ b_ih0,
    const float* __restrict__ xp1,
    const int*   __restrict__ trg,
    const float* __restrict__ sh,
    float* __restrict__ out)
{
    __shared__ __align__(16) float4 wNs[8192];      // 128KB: [kk 0..15][t 0..511]
    __shared__ __align__(16) _Float16 hbuf[2][256];
    __shared__ __align__(16) float bitL[1024];
    int b = blockIdx.x, t = threadIdx.x;
    int d = t >> 1, half = t & 1;

    if (LAYER == 0) {
        #pragma unroll
        for (int i = 0; i < 2; ++i) {
            int idx = t + i*512;
            bitL[idx] = (idx == 0) ? 1.0f : (float)trg[b*1024 + idx - 1];
        }
    }

    // --- wN K-half of row d -> LDS (f16 packed), once; linear, conflict-free ---
    {
        const float2* src = (const float2*)(w_hh + (size_t)(512 + d)*256 + half*128);
        #pragma unroll
        for (int kk = 0; kk < 16; ++kk) {
            h2 p0 = cvt2(src[kk*4+0]), p1 = cvt2(src[kk*4+1]);
            h2 p2 = cvt2(src[kk*4+2]), p3 = cvt2(src[kk*4+3]);
            float4 v;
            v.x = __builtin_bit_cast(float, p0); v.y = __builtin_bit_cast(float, p1);
            v.z = __builtin_bit_cast(float, p2); v.w = __builtin_bit_cast(float, p3);
            wNs[kk*512 + t] = v;
        }
    }
    // --- wR, wZ K-halves -> registers (f16 packed) ---
    h2 wR[64], wZ[64];
    {
        const float2* wr = (const float2*)(w_hh + (size_t)d*256       + half*128);
        const float2* wz = (const float2*)(w_hh + (size_t)(d+256)*256 + half*128);
        #pragma unroll
        for (int k = 0; k < 64; ++k) { wR[k] = cvt2(wr[k]); wZ[k] = cvt2(wz[k]); }
    }
    float bhr = b_hh[d], bhz = b_hh[256 + d], bhn = b_hh[512 + d];
    float wir=0.f, wiz=0.f, win=0.f, bir=0.f, biz=0.f, bin=0.f;
    if (LAYER == 0) {
        wir = w_ih0[d]; wiz = w_ih0[256 + d]; win = w_ih0[512 + d];
        bir = b_ih0[d]; biz = b_ih0[256 + d]; bin = b_ih0[512 + d];
    }

    float hreg = sh[b*256 + d];
    if (half == 0) hbuf[0][hperm(d)] = (_Float16)hreg;

    float xr, xz, xn;
    if (LAYER == 1) {
        size_t base = (size_t)b*768;
        xr = xp1[base + d]; xz = xp1[base + 256 + d]; xn = xp1[base + 512 + d];
    }
    __syncthreads();

    for (int l = 0; l < 1024; ++l) {
        // prefetch next step's xp (stays in flight across the lgkm-only barrier)
        float nxr, nxz, nxn;
        if (LAYER == 1) {
            int ln = (l < 1023) ? (l + 1) : 1023;
            size_t base = ((size_t)ln*32 + b)*768;
            nxr = xp1[base + d]; nxz = xp1[base + 256 + d]; nxn = xp1[base + 512 + d];
        }
        // --- partial dots over this thread's K-half ---
        const float4* hb4 = (const float4*)(&hbuf[l & 1][0]);
        float ar = 0.f, az = 0.f, an = 0.f;
        #pragma unroll
        for (int kk = 0; kk < 16; ++kk) {
            // permuted slot holding dims half*128 + kk*8 .. +8 (wave broadcast)
            float4 hv = hb4[(kk & 7)*4 + half*2 + (kk >> 3)];
            float4 wv = wNs[kk*512 + t];            // wN, conflict-free private
            h2 h0 = __builtin_bit_cast(h2, hv.x);
            h2 h1 = __builtin_bit_cast(h2, hv.y);
            h2 hc = __builtin_bit_cast(h2, hv.z);
            h2 h3 = __builtin_bit_cast(h2, hv.w);
            ar = dot2(wR[4*kk+0], h0, ar); ar = dot2(wR[4*kk+1], h1, ar);
            ar = dot2(wR[4*kk+2], hc, ar); ar = dot2(wR[4*kk+3], h3, ar);
            az = dot2(wZ[4*kk+0], h0, az); az = dot2(wZ[4*kk+1], h1, az);
            az = dot2(wZ[4*kk+2], hc, az); az = dot2(wZ[4*kk+3], h3, az);
            an = dot2(__builtin_bit_cast(h2, wv.x), h0, an);
            an = dot2(__builtin_bit_cast(h2, wv.y), h1, an);
            an = dot2(__builtin_bit_cast(h2, wv.z), hc, an);
            an = dot2(__builtin_bit_cast(h2, wv.w), h3, an);
        }
        // combine K-halves (partner = lane^1, same wave)
        ar += __shfl_xor(ar, 1);
        az += __shfl_xor(az, 1);
        an += __shfl_xor(an, 1);
        // --- gates (both lanes of the pair compute identically) ---
        if (LAYER == 0) {
            float bit = bitL[l];
            xr = bir + bit*wir; xz = biz + bit*wiz; xn = bin + bit*win;
        }
        float r = sigm(xr + ar + bhr);
        float z = sigm(xz + az + bhz);
        float n = tanhf(xn + r*(an + bhn));
        hreg = (1.0f - z)*n + z*hreg;
        if (half == 0) {
            hbuf[(l + 1) & 1][hperm(d)] = (_Float16)hreg;
        } else {
            size_t oidx = (LAYER == 0) ? (((size_t)l*32 + b)*256 + d)
                                       : (((size_t)b*1024 + l)*256 + d);
            out[oidx] = hreg;
        }
        wg_barrier();
        if (LAYER == 1) { xr = nxr; xz = nxz; xn = nxn; }
    }
}

// ---------------- f16 MFMA GEMM: C[M,N] = act(A[M,K] @ B[N,K]^T + bias) ----------------
// 128x128 tile, 256 threads (4 waves); wave w -> 64x64 quadrant (wm=w>>1, wn=w&1).
// fp32 global -> f16 LDS staging (rows padded to 40 f16: 16B-aligned b128 frag
// reads, <=2-way bank aliasing). Fragment conventions verified on-device (R8):
// A-frag lane l: A[m + (l&15)][kt + (l>>4)*8 + j]; C row=(l>>4)*4+reg, col=l&15.
// aMode 0: plain A. aMode 3 (comb): K=768, part 0 ctx / 1 outs / 2 sh(row=m>>10).
__global__ __launch_bounds__(256, 3) void k_gemm_mfma(
    const float* __restrict__ A, const float* __restrict__ B,
    const float* __restrict__ bias, float* __restrict__ C,
    int M, int N, int K, int act, int aMode,
    const float* __restrict__ A1, const float* __restrict__ A2)
{
    __shared__ __align__(16) _Float16 As[128][40];
    __shared__ __align__(16) _Float16 Bs[128][40];
    int nbn = N >> 7;
    int bx = blockIdx.x % nbn, by = blockIdx.x / nbn;
    int m0 = by << 7, n0 = bx << 7;
    int t = threadIdx.x;
    int w = t >> 6, l = t & 63;
    int wm = w >> 1, wn = w & 1;
    int lc = l & 15, lg = l >> 4;
    f32x4 acc[4][4] = {};
    for (int kt = 0; kt < K; kt += 32) {
        __syncthreads();
        #pragma unroll
        for (int p = 0; p < 4; ++p) {
            int slot = t + p*256;            // 1024 slots: (m, kc)
            int m = slot >> 3, kc = slot & 7;
            int gk = kt + kc*4;
            float4 va;
            if (aMode == 0) {
                va = *(const float4*)(A + (size_t)(m0+m)*K + gk);
            } else {
                int part = gk >> 8, kk = gk & 255;
                const float* P = (part == 0) ? A : ((part == 1) ? A1 : A2);
                int row = (part == 2) ? ((m0+m) >> 10) : (m0+m);
                va = *(const float4*)(P + (size_t)row*256 + kk);
            }
            h2 pa; pa[0] = (_Float16)va.x; pa[1] = (_Float16)va.y;
            h2 pb; pb[0] = (_Float16)va.z; pb[1] = (_Float16)va.w;
            *(float2*)(&As[m][kc*4]) = make_float2(__builtin_bit_cast(float, pa),
                                                   __builtin_bit_cast(float, pb));
            float4 vb = *(const float4*)(B + (size_t)(n0+m)*K + gk);
            h2 qa; qa[0] = (_Float16)vb.x; qa[1] = (_Float16)vb.y;
            h2 qb; qb[0] = (_Float16)vb.z; qb[1] = (_Float16)vb.w;
            *(float2*)(&Bs[m][kc*4]) = make_float2(__builtin_bit_cast(float, qa),
                                                   __builtin_bit_cast(float, qb));
        }
        __syncthreads();
        f16x8 af[4], bf[4];
        #pragma unroll
        for (int mt = 0; mt < 4; ++mt)
            af[mt] = *(const f16x8*)(&As[wm*64 + mt*16 + lc][lg*8]);
        #pragma unroll
        for (int nt = 0; nt < 4; ++nt)
            bf[nt] = *(const f16x8*)(&Bs[wn*64 + nt*16 + lc][lg*8]);
        #pragma unroll
        for (int mt = 0; mt < 4; ++mt)
            #pragma unroll
            for (int nt = 0; nt < 4; ++nt)
                acc[mt][nt] = __builtin_amdgcn_mfma_f32_16x16x32_f16(af[mt], bf[nt], acc[mt][nt], 0, 0, 0);
    }
    #pragma unroll
    for (int nt = 0; nt < 4; ++nt) {
        int col = n0 + wn*64 + nt*16 + lc;
        float bv = bias[col];
        #pragma unroll
        for (int mt = 0; mt < 4; ++mt) {
            int rbase = m0 + wm*64 + mt*16 + lg*4;
            #pragma unroll
            for (int r = 0; r < 4; ++r) {
                float v = acc[mt][nt][r] + bv;
                if (act == 1) v = geluf(v);
                else if (act == 2) v = tanhf(v);
                C[(size_t)(rbase + r)*N + col] = v;
            }
        }
    }
}

// ---------------- causal attention (flash-style), WG = (b, 16 rows) ----------------
__global__ __launch_bounds__(256) void k_attn(
    const float* __restrict__ outs, const float* __restrict__ modif, float* __restrict__ ctx)
{
    __shared__ __align__(16) float Qs[16][256];
    __shared__ __align__(16) float KVs[32][256];
    __shared__ __align__(16) float sS[16][32];
    __shared__ float rowScaleL[16];
    __shared__ float rowLL[16];
    int b = blockIdx.y, l0 = blockIdx.x << 4, t = threadIdx.x;
    for (int idx = t; idx < 1024; idx += 256) {
        int r = idx >> 6, k4 = idx & 63;
        *(float4*)&Qs[r][k4*4] = *(const float4*)(outs + ((size_t)b*1024 + l0 + r)*256 + k4*4);
    }
    int sr = t >> 4, sj = t & 15;
    int rp = t >> 5, cg = t & 31;
    float rowM = -1e30f, rowL = 0.f;
    float accA[8] = {}, accB[8] = {};
    int nt = ((l0 + 14) >> 5) + 1;
    for (int tt = 0; tt < nt; ++tt) {
        int m0 = tt << 5;
        __syncthreads();
        for (int idx = t; idx < 2048; idx += 256) {
            int mm = idx >> 6, k4 = idx & 63;
            *(float4*)&KVs[mm][k4*4] = *(const float4*)(modif + ((size_t)b*1024 + m0 + mm)*256 + k4*4);
        }
        __syncthreads();
        {
            int mp = sj << 1;
            const float4* q4 = (const float4*)Qs[sr];
            const float4* x4 = (const float4*)KVs[mp];
            const float4* y4 = (const float4*)KVs[mp+1];
            float s0 = 0.f, s1 = 0.f;
            #pragma unroll 8
            for (int kk = 0; kk < 64; ++kk) {
                int k = (kk + sj) & 63;
                float4 q = q4[k], x = x4[k], y = y4[k];
                s0 += q.x*x.x + q.y*x.y + q.z*x.z + q.w*x.w;
                s1 += q.x*y.x + q.y*y.y + q.z*y.z + q.w*y.w;
            }
            int l = l0 + sr;
            if (m0 + mp     >= l) s0 = -1e30f;
            if (m0 + mp + 1 >= l) s1 = -1e30f;
            sS[sr][mp] = s0; sS[sr][mp+1] = s1;
        }
        __syncthreads();
        {
            float v0 = sS[sr][sj], v1 = sS[sr][sj+16];
            float mx = fmaxf(v0, v1);
            for (int off = 8; off; off >>= 1) mx = fmaxf(mx, __shfl_xor(mx, off));
            float newM = fmaxf(rowM, mx);
            float scale, p0, p1;
            if (newM < -1e29f) { scale = 1.f; p0 = 0.f; p1 = 0.f; }
            else { scale = expf(rowM - newM); p0 = expf(v0 - newM); p1 = expf(v1 - newM); }
            rowM = newM;
            float ts = p0 + p1;
            for (int off = 8; off; off >>= 1) ts += __shfl_xor(ts, off);
            rowL = rowL*scale + ts;
            sS[sr][sj] = p0; sS[sr][sj+16] = p1;
            if (sj == 0) { rowScaleL[sr] = scale; rowLL[sr] = rowL; }
        }
        __syncthreads();
        for (int idx = t; idx < 2048; idx += 256) {
            int mm = idx >> 6, k4 = idx & 63;
            *(float4*)&KVs[mm][k4*4] = *(const float4*)(outs + ((size_t)b*1024 + m0 + mm)*256 + k4*4);
        }
        __syncthreads();
        {
            float sc0 = rowScaleL[2*rp], sc1 = rowScaleL[2*rp+1];
            #pragma unroll
            for (int j = 0; j < 8; ++j) { accA[j] *= sc0; accB[j] *= sc1; }
            int c0 = cg << 3;
            #pragma unroll 4
            for (int mm = 0; mm < 32; ++mm) {
                float p0 = sS[2*rp][mm], p1 = sS[2*rp+1][mm];
                float4 vA = *(const float4*)&KVs[mm][c0];
                float4 vB = *(const float4*)&KVs[mm][c0+4];
                accA[0] += p0*vA.x; accA[1] += p0*vA.y; accA[2] += p0*vA.z; accA[3] += p0*vA.w;
                accA[4] += p0*vB.x; accA[5] += p0*vB.y; accA[6] += p0*vB.z; accA[7] += p0*vB.w;
                accB[0] += p1*vA.x; accB[1] += p1*vA.y; accB[2] += p1*vA.z; accB[3] += p1*vA.w;
                accB[4] += p1*vB.x; accB[5] += p1*vB.y; accB[6] += p1*vB.z; accB[7] += p1*vB.w;
            }
        }
    }
    __syncthreads();
    int c0 = cg << 3;
    {
        int l = l0 + 2*rp;
        float inv = (l == 0) ? 0.f : 1.f/rowLL[2*rp];
        float4* cp = (float4*)(ctx + ((size_t)b*1024 + l)*256 + c0);
        cp[0] = make_float4(accA[0]*inv, accA[1]*inv, accA[2]*inv, accA[3]*inv);
        cp[1] = make_float4(accA[4]*inv, accA[5]*inv, accA[6]*inv, accA[7]*inv);
    }
    {
        int l = l0 + 2*rp + 1;
        float inv = 1.f/rowLL[2*rp+1];
        float4* cp = (float4*)(ctx + ((size_t)b*1024 + l)*256 + c0);
        cp[0] = make_float4(accB[0]*inv, accB[1]*inv, accB[2]*inv, accB[3]*inv);
        cp[1] = make_float4(accB[4]*inv, accB[5]*inv, accB[6]*inv, accB[7]*inv);
    }
}

// ---------------- final: logits + outputs ----------------
__global__ __launch_bounds__(256) void k_final(
    const float* __restrict__ h2v, const float* __restrict__ w2, const float* __restrict__ b2,
    const float* __restrict__ mask, float* __restrict__ out)
{
    int i = blockIdx.x*256 + threadIdx.x;   // < 32768
    const float4* h4 = (const float4*)(h2v + (size_t)i*256);
    const float4* w4 = (const float4*)w2;
    float a0=0,a1=0,a2=0,a3=0;
    #pragma unroll 8
    for (int k = 0; k < 64; ++k) {
        float4 h = h4[k], w = w4[k];
        a0 += h.x*w.x; a1 += h.y*w.y; a2 += h.z*w.z; a3 += h.w*w.w;
    }
    float lg = a0+a1+a2+a3 + b2[0];
    float p = sigm(lg);
    out[2*i]     = 1.0f - p;
    out[2*i + 1] = p;
    out[65536  + i] = (lg > 0.f) ? 1.0f : ((lg < 0.f) ? -1.0f : 0.0f);
    out[98304  + i] = mask[i];
    out[131072 + i] = lg;
}

extern "C" void kernel_launch(void* const* d_in, const int* in_sizes, int n_in,
                              void* d_out, int out_size, void* d_ws, size_t ws_size,
                              hipStream_t stream)
{
    const float* ne      = (const float*)d_in[0];
    const float* mask    = (const float*)d_in[1];
    const int*   trg     = (const int*)  d_in[2];
    const float* se_w0   = (const float*)d_in[3];
    const float* se_b0   = (const float*)d_in[4];
    const float* se_w1   = (const float*)d_in[5];
    const float* se_b1   = (const float*)d_in[6];
    const float* se_w2   = (const float*)d_in[7];
    const float* se_b2   = (const float*)d_in[8];
    const float* w_ih0   = (const float*)d_in[9];
    const float* w_hh0   = (const float*)d_in[10];
    const float* b_ih0   = (const float*)d_in[11];
    const float* b_hh0   = (const float*)d_in[12];
    const float* w_ih1   = (const float*)d_in[13];
    const float* w_hh1   = (const float*)d_in[14];
    const float* b_ih1   = (const float*)d_in[15];
    const float* b_hh1   = (const float*)d_in[16];
    const float* attn_w1 = (const float*)d_in[17];
    const float* attn_b1 = (const float*)d_in[18];
    const float* comb_w  = (const float*)d_in[19];
    const float* comb_b  = (const float*)d_in[20];
    const float* dec_w0  = (const float*)d_in[21];
    const float* dec_b0  = (const float*)d_in[22];
    const float* dec_w1  = (const float*)d_in[23];
    const float* dec_b1  = (const float*)d_in[24];
    const float* dec_w2  = (const float*)d_in[25];
    const float* dec_b2  = (const float*)d_in[26];

    float* W    = (float*)d_ws;
    float* sh   = W;                    // 8192
    float* o0   = W + 8192;             // [L,B,D] 8388608
    float* xp1  = W + 8396800;          // [L,B,G] 25165824
    float* outs = W + 33562624;         // [B,L,D] 8388608  (total 41951232 floats = 160 MB)
    float* modif = o0;                  // reuse (o0 dead after xp1 GEMM)
    float* ctx  = xp1;                  // reuse (xp1 dead after scan1)
    float* dec  = xp1 + 8388608;
    float* h1   = xp1 + 16777216;
    float* h2b  = o0;                   // reuse (modif dead after attention)
    float* out  = (float*)d_out;

    k_start_embed<<<32, 256, 0, stream>>>(ne, se_w0, se_b0, se_w1, se_b1, se_w2, se_b2, sh);
    k_gru3<0><<<32, 512, 0, stream>>>(w_hh0, b_hh0, w_ih0, b_ih0, nullptr, trg, sh, o0);
    k_gemm_mfma<<<1536, 256, 0, stream>>>(o0, w_ih1, b_ih1, xp1, NROWS, 768, 256, 0, 0, nullptr, nullptr);
    k_gru3<1><<<32, 512, 0, stream>>>(w_hh1, b_hh1, nullptr, nullptr, xp1, trg, sh, outs);
    k_gemm_mfma<<<512, 256, 0, stream>>>(outs, attn_w1, attn_b1, modif, NROWS, 256, 256, 0, 0, nullptr, nullptr);
    { dim3 ag(64, 32); k_attn<<<ag, 256, 0, stream>>>(outs, modif, ctx); }
    k_gemm_mfma<<<512, 256, 0, stream>>>(ctx, comb_w, comb_b, dec, NROWS, 256, 768, 2, 3, outs, sh);
    k_gemm_mfma<<<512, 256, 0, stream>>>(dec, dec_w0, dec_b0, h1, NROWS, 256, 256, 1, 0, nullptr, nullptr);
    k_gemm_mfma<<<512, 256, 0, stream>>>(h1, dec_w1, dec_b1, h2b, NROWS, 256, 256, 1, 0, nullptr, nullptr);
    k_final<<<128, 256, 0, stream>>>(h2b, dec_w2, dec_b2, mask, out);
}

// Round 12
// 3434.809 us; speedup vs baseline: 1.1201x; 1.1201x over previous
//
#include <hip/hip_runtime.h>
#include <math.h>

// B=32, L=1024, D=256, G=768
#define NROWS 32768  // B*L

typedef float v4 __attribute__((ext_vector_type(4)));
typedef _Float16 h2 __attribute__((ext_vector_type(2)));
typedef _Float16 f16x8 __attribute__((ext_vector_type(8)));
typedef float f32x4 __attribute__((ext_vector_type(4)));

__device__ __forceinline__ float geluf(float x){ return 0.5f*x*(1.0f+erff(x*0.70710678118654752f)); }

// ---- fast transcendentals: native v_exp_f32 (exp2) + v_rcp_f32 ----
// libm expf/tanhf are 15-40 instr each (IEEE div, range fixup) and spike
// register pressure; these are 4-5 VALU with correct +-inf saturation.
__device__ __forceinline__ float fexp2(float x){
#if __has_builtin(__builtin_amdgcn_exp2f)
    return __builtin_amdgcn_exp2f(x);
#else
    return exp2f(x);
#endif
}
__device__ __forceinline__ float frcp(float x){
#if __has_builtin(__builtin_amdgcn_rcpf)
    return __builtin_amdgcn_rcpf(x);
#else
    return 1.0f/x;
#endif
}
#define LOG2E 1.44269504088896f
__device__ __forceinline__ float fexp(float x){ return fexp2(x*LOG2E); }
__device__ __forceinline__ float sigm(float x){ return frcp(1.0f + fexp2(-LOG2E*x)); }
__device__ __forceinline__ float ftanh(float x){ return 1.0f - 2.0f*frcp(fexp2(2.0f*LOG2E*x) + 1.0f); }

__device__ __forceinline__ float dot2(h2 a, h2 b, float c){
#if __has_builtin(__builtin_amdgcn_fdot2)
    return __builtin_amdgcn_fdot2(a, b, c, false);
#else
    return c + (float)a.x*(float)b.x + (float)a.y*(float)b.y;
#endif
}
__device__ __forceinline__ h2 cvt2(float2 a){ return h2{(_Float16)a.x, (_Float16)a.y}; }

// barrier that does NOT drain vmcnt: LDS visibility only. Global prefetch
// loads / output stores stay in flight across it.
__device__ __forceinline__ void wg_barrier(){
    asm volatile("s_waitcnt lgkmcnt(0)" ::: "memory");
    __builtin_amdgcn_s_barrier();
    __builtin_amdgcn_sched_barrier(0);
}

// ---------------- start embed: sh[b,d] ----------------
__global__ __launch_bounds__(256) void k_start_embed(
    const float* __restrict__ ne, const float* __restrict__ w0, const float* __restrict__ b0,
    const float* __restrict__ w1, const float* __restrict__ b1,
    const float* __restrict__ w2, const float* __restrict__ b2,
    float* __restrict__ sh)
{
    __shared__ __align__(16) float encL[1024];
    __shared__ __align__(16) float g1[256];
    __shared__ __align__(16) float g2[256];
    int b = blockIdx.x, t = threadIdx.x;
    for (int i = t; i < 1024; i += 256) encL[i] = ne[b*1024 + i];
    __syncthreads();
    const float4* wr = (const float4*)(w0 + (size_t)t*1024);
    const float4* e4 = (const float4*)encL;
    float a0=0,a1=0,a2=0,a3=0;
    #pragma unroll 8
    for (int k = 0; k < 256; ++k){ float4 w = wr[k], e = e4[k];
        a0 += w.x*e.x; a1 += w.y*e.y; a2 += w.z*e.z; a3 += w.w*e.w; }
    float t1 = a0+a1+a2+a3 + b0[t];
    float res = t1;
    g1[t] = geluf(t1);
    __syncthreads();
    const float4* w1r = (const float4*)(w1 + (size_t)t*256);
    const float4* g14 = (const float4*)g1;
    a0=a1=a2=a3=0.f;
    #pragma unroll 8
    for (int k = 0; k < 64; ++k){ float4 w = w1r[k], e = g14[k];
        a0 += w.x*e.x; a1 += w.y*e.y; a2 += w.z*e.z; a3 += w.w*e.w; }
    g2[t] = geluf(a0+a1+a2+a3 + b1[t]);
    __syncthreads();
    const float4* w2r = (const float4*)(w2 + (size_t)t*256);
    const float4* g24 = (const float4*)g2;
    a0=a1=a2=a3=0.f;
    #pragma unroll 8
    for (int k = 0; k < 64; ++k){ float4 w = w2r[k], e = g24[k];
        a0 += w.x*e.x; a1 += w.y*e.y; a2 += w.z*e.z; a3 += w.w*e.w; }
    sh[b*256 + t] = a0+a1+a2+a3 + b2[t] + res;
}

// permuted f16 index within an hbuf row for hidden dim:
// dim = (hi:2)(mid:3)(lo:3) -> idx = mid*32 + hi*8 + lo  (bijective).
__device__ __forceinline__ int hperm(int dim){
    return ((dim >> 3) & 7)*32 + ((dim >> 6) << 3) + (dim & 7);
}

// ---------------- GRU scan v12: v11 + fast gates + reg-trimmed prefetch ----------------
// 512 threads; thread (d = t>>1, half = t&1) owns gate rows d (r), d+256 (z),
// d+512 (n) over K-half [half*128, +128). wR+wZ halves in regs (128 h2),
// wN in LDS (128KB, wNs[kk][t], consecutive 16B/lane, conflict-free).
// v12: gates use native exp2/rcp (4-5 VALU each vs 15-40 libm, lower live
// pressure -> less spill); next-step xp loaded INTO xr/xz/xn right after the
// gates consume them (-3 live regs, same in-flight-across-barrier effect).
template<int LAYER>
__global__ __launch_bounds__(512) void k_gru3(
    const float* __restrict__ w_hh, const float* __restrict__ b_hh,
    const float* __restrict__ w_ih0, const float* __restrict__ b_ih0,
    const float* __restrict__ xp1,
    const int*   __restrict__ trg,
    const float* __restrict__ sh,
    float* __restrict__ out)
{
    __shared__ __align__(16) float4 wNs[8192];      // 128KB: [kk 0..15][t 0..511]
    __shared__ __align__(16) _Float16 hbuf[2][256];
    __shared__ __align__(16) float bitL[1024];
    int b = blockIdx.x, t = threadIdx.x;
    int d = t >> 1, half = t & 1;

    if (LAYER == 0) {
        #pragma unroll
        for (int i = 0; i < 2; ++i) {
            int idx = t + i*512;
            bitL[idx] = (idx == 0) ? 1.0f : (float)trg[b*1024 + idx - 1];
        }
    }

    // --- wN K-half of row d -> LDS (f16 packed), once; linear, conflict-free ---
    {
        const float2* src = (const float2*)(w_hh + (size_t)(512 + d)*256 + half*128);
        #pragma unroll
        for (int kk = 0; kk < 16; ++kk) {
            h2 p0 = cvt2(src[kk*4+0]), p1 = cvt2(src[kk*4+1]);
            h2 p2 = cvt2(src[kk*4+2]), p3 = cvt2(src[kk*4+3]);
            float4 v;
            v.x = __builtin_bit_cast(float, p0); v.y = __builtin_bit_cast(float, p1);
            v.z = __builtin_bit_cast(float, p2); v.w = __builtin_bit_cast(float, p3);
            wNs[kk*512 + t] = v;
        }
    }
    // --- wR, wZ K-halves -> registers (f16 packed) ---
    h2 wR[64], wZ[64];
    {
        const float2* wr = (const float2*)(w_hh + (size_t)d*256       + half*128);
        const float2* wz = (const float2*)(w_hh + (size_t)(d+256)*256 + half*128);
        #pragma unroll
        for (int k = 0; k < 64; ++k) { wR[k] = cvt2(wr[k]); wZ[k] = cvt2(wz[k]); }
    }
    float bhr = b_hh[d], bhz = b_hh[256 + d], bhn = b_hh[512 + d];
    float wir=0.f, wiz=0.f, win=0.f, bir=0.f, biz=0.f, bin=0.f;
    if (LAYER == 0) {
        wir = w_ih0[d]; wiz = w_ih0[256 + d]; win = w_ih0[512 + d];
        bir = b_ih0[d]; biz = b_ih0[256 + d]; bin = b_ih0[512 + d];
    }

    float hreg = sh[b*256 + d];
    if (half == 0) hbuf[0][hperm(d)] = (_Float16)hreg;

    float xr = 0.f, xz = 0.f, xn = 0.f;
    if (LAYER == 1) {
        size_t base = (size_t)b*768;
        xr = xp1[base + d]; xz = xp1[base + 256 + d]; xn = xp1[base + 512 + d];
    }
    __syncthreads();

    for (int l = 0; l < 1024; ++l) {
        // --- partial dots over this thread's K-half ---
        const float4* hb4 = (const float4*)(&hbuf[l & 1][0]);
        float ar = 0.f, az = 0.f, an = 0.f;
        #pragma unroll
        for (int kk = 0; kk < 16; ++kk) {
            float4 hv = hb4[(kk & 7)*4 + half*2 + (kk >> 3)];  // wave 2-addr broadcast
            float4 wv = wNs[kk*512 + t];                       // conflict-free private
            h2 h0 = __builtin_bit_cast(h2, hv.x);
            h2 h1 = __builtin_bit_cast(h2, hv.y);
            h2 hc = __builtin_bit_cast(h2, hv.z);
            h2 h3 = __builtin_bit_cast(h2, hv.w);
            ar = dot2(wR[4*kk+0], h0, ar); ar = dot2(wR[4*kk+1], h1, ar);
            ar = dot2(wR[4*kk+2], hc, ar); ar = dot2(wR[4*kk+3], h3, ar);
            az = dot2(wZ[4*kk+0], h0, az); az = dot2(wZ[4*kk+1], h1, az);
            az = dot2(wZ[4*kk+2], hc, az); az = dot2(wZ[4*kk+3], h3, az);
            an = dot2(__builtin_bit_cast(h2, wv.x), h0, an);
            an = dot2(__builtin_bit_cast(h2, wv.y), h1, an);
            an = dot2(__builtin_bit_cast(h2, wv.z), hc, an);
            an = dot2(__builtin_bit_cast(h2, wv.w), h3, an);
        }
        // combine K-halves (partner = lane^1, same wave)
        ar += __shfl_xor(ar, 1);
        az += __shfl_xor(az, 1);
        an += __shfl_xor(an, 1);
        // --- gates (fast native exp2/rcp) ---
        if (LAYER == 0) {
            float bit = bitL[l];
            xr = bir + bit*wir; xz = biz + bit*wiz; xn = bin + bit*win;
        }
        float r = sigm(xr + ar + bhr);
        float z = sigm(xz + az + bhz);
        float n = ftanh(xn + r*(an + bhn));
        hreg = (1.0f - z)*n + z*hreg;
        if (half == 0) {
            hbuf[(l + 1) & 1][hperm(d)] = (_Float16)hreg;
        } else {
            size_t oidx = (LAYER == 0) ? (((size_t)l*32 + b)*256 + d)
                                       : (((size_t)b*1024 + l)*256 + d);
            out[oidx] = hreg;
        }
        // load NEXT step's xp into the now-dead xr/xz/xn (in flight across barrier)
        if (LAYER == 1) {
            int ln = (l < 1023) ? (l + 1) : 1023;
            size_t base = ((size_t)ln*32 + b)*768;
            xr = xp1[base + d]; xz = xp1[base + 256 + d]; xn = xp1[base + 512 + d];
        }
        wg_barrier();
    }
}

// ---------------- f16 MFMA GEMM: C[M,N] = act(A[M,K] @ B[N,K]^T + bias) ----------------
// 128x128 tile, 256 threads (4 waves); wave w -> 64x64 quadrant (wm=w>>1, wn=w&1).
// fp32 global -> f16 LDS staging. Fragment conventions verified on-device (R8).
// aMode 0: plain A. aMode 3 (comb): K=768, part 0 ctx / 1 outs / 2 sh(row=m>>10).
__global__ __launch_bounds__(256, 3) void k_gemm_mfma(
    const float* __restrict__ A, const float* __restrict__ B,
    const float* __restrict__ bias, float* __restrict__ C,
    int M, int N, int K, int act, int aMode,
    const float* __restrict__ A1, const float* __restrict__ A2)
{
    __shared__ __align__(16) _Float16 As[128][40];
    __shared__ __align__(16) _Float16 Bs[128][40];
    int nbn = N >> 7;
    int bx = blockIdx.x % nbn, by = blockIdx.x / nbn;
    int m0 = by << 7, n0 = bx << 7;
    int t = threadIdx.x;
    int w = t >> 6, l = t & 63;
    int wm = w >> 1, wn = w & 1;
    int lc = l & 15, lg = l >> 4;
    f32x4 acc[4][4] = {};
    for (int kt = 0; kt < K; kt += 32) {
        __syncthreads();
        #pragma unroll
        for (int p = 0; p < 4; ++p) {
            int slot = t + p*256;            // 1024 slots: (m, kc)
            int m = slot >> 3, kc = slot & 7;
            int gk = kt + kc*4;
            float4 va;
            if (aMode == 0) {
                va = *(const float4*)(A + (size_t)(m0+m)*K + gk);
            } else {
                int part = gk >> 8, kk = gk & 255;
                const float* P = (part == 0) ? A : ((part == 1) ? A1 : A2);
                int row = (part == 2) ? ((m0+m) >> 10) : (m0+m);
                va = *(const float4*)(P + (size_t)row*256 + kk);
            }
            h2 pa; pa[0] = (_Float16)va.x; pa[1] = (_Float16)va.y;
            h2 pb; pb[0] = (_Float16)va.z; pb[1] = (_Float16)va.w;
            *(float2*)(&As[m][kc*4]) = make_float2(__builtin_bit_cast(float, pa),
                                                   __builtin_bit_cast(float, pb));
            float4 vb = *(const float4*)(B + (size_t)(n0+m)*K + gk);
            h2 qa; qa[0] = (_Float16)vb.x; qa[1] = (_Float16)vb.y;
            h2 qb; qb[0] = (_Float16)vb.z; qb[1] = (_Float16)vb.w;
            *(float2*)(&Bs[m][kc*4]) = make_float2(__builtin_bit_cast(float, qa),
                                                   __builtin_bit_cast(float, qb));
        }
        __syncthreads();
        f16x8 af[4], bf[4];
        #pragma unroll
        for (int mt = 0; mt < 4; ++mt)
            af[mt] = *(const f16x8*)(&As[wm*64 + mt*16 + lc][lg*8]);
        #pragma unroll
        for (int nt = 0; nt < 4; ++nt)
            bf[nt] = *(const f16x8*)(&Bs[wn*64 + nt*16 + lc][lg*8]);
        #pragma unroll
        for (int mt = 0; mt < 4; ++mt)
            #pragma unroll
            for (int nt = 0; nt < 4; ++nt)
                acc[mt][nt] = __builtin_amdgcn_mfma_f32_16x16x32_f16(af[mt], bf[nt], acc[mt][nt], 0, 0, 0);
    }
    #pragma unroll
    for (int nt = 0; nt < 4; ++nt) {
        int col = n0 + wn*64 + nt*16 + lc;
        float bv = bias[col];
        #pragma unroll
        for (int mt = 0; mt < 4; ++mt) {
            int rbase = m0 + wm*64 + mt*16 + lg*4;
            #pragma unroll
            for (int r = 0; r < 4; ++r) {
                float v = acc[mt][nt][r] + bv;
                if (act == 1) v = geluf(v);
                else if (act == 2) v = ftanh(v);
                C[(size_t)(rbase + r)*N + col] = v;
            }
        }
    }
}

// ---------------- causal attention (flash-style), WG = (b, 16 rows) ----------------
__global__ __launch_bounds__(256) void k_attn(
    const float* __restrict__ outs, const float* __restrict__ modif, float* __restrict__ ctx)
{
    __shared__ __align__(16) float Qs[16][256];
    __shared__ __align__(16) float KVs[32][256];
    __shared__ __align__(16) float sS[16][32];
    __shared__ float rowScaleL[16];
    __shared__ float rowLL[16];
    int b = blockIdx.y, l0 = blockIdx.x << 4, t = threadIdx.x;
    for (int idx = t; idx < 1024; idx += 256) {
        int r = idx >> 6, k4 = idx & 63;
        *(float4*)&Qs[r][k4*4] = *(const float4*)(outs + ((size_t)b*1024 + l0 + r)*256 + k4*4);
    }
    int sr = t >> 4, sj = t & 15;
    int rp = t >> 5, cg = t & 31;
    float rowM = -1e30f, rowL = 0.f;
    float accA[8] = {}, accB[8] = {};
    int nt = ((l0 + 14) >> 5) + 1;
    for (int tt = 0; tt < nt; ++tt) {
        int m0 = tt << 5;
        __syncthreads();
        for (int idx = t; idx < 2048; idx += 256) {
            int mm = idx >> 6, k4 = idx & 63;
            *(float4*)&KVs[mm][k4*4] = *(const float4*)(modif + ((size_t)b*1024 + m0 + mm)*256 + k4*4);
        }
        __syncthreads();
        {
            int mp = sj << 1;
            const float4* q4 = (const float4*)Qs[sr];
            const float4* x4 = (const float4*)KVs[mp];
            const float4* y4 = (const float4*)KVs[mp+1];
            float s0 = 0.f, s1 = 0.f;
            #pragma unroll 8
            for (int kk = 0; kk < 64; ++kk) {
                int k = (kk + sj) & 63;
                float4 q = q4[k], x = x4[k], y = y4[k];
                s0 += q.x*x.x + q.y*x.y + q.z*x.z + q.w*x.w;
                s1 += q.x*y.x + q.y*y.y + q.z*y.z + q.w*y.w;
            }
            int l = l0 + sr;
            if (m0 + mp     >= l) s0 = -1e30f;
            if (m0 + mp + 1 >= l) s1 = -1e30f;
            sS[sr][mp] = s0; sS[sr][mp+1] = s1;
        }
        __syncthreads();
        {
            float v0 = sS[sr][sj], v1 = sS[sr][sj+16];
            float mx = fmaxf(v0, v1);
            for (int off = 8; off; off >>= 1) mx = fmaxf(mx, __shfl_xor(mx, off));
            float newM = fmaxf(rowM, mx);
            float scale, p0, p1;
            if (newM < -1e29f) { scale = 1.f; p0 = 0.f; p1 = 0.f; }
            else { scale = fexp(rowM - newM); p0 = fexp(v0 - newM); p1 = fexp(v1 - newM); }
            rowM = newM;
            float ts = p0 + p1;
            for (int off = 8; off; off >>= 1) ts += __shfl_xor(ts, off);
            rowL = rowL*scale + ts;
            sS[sr][sj] = p0; sS[sr][sj+16] = p1;
            if (sj == 0) { rowScaleL[sr] = scale; rowLL[sr] = rowL; }
        }
        __syncthreads();
        for (int idx = t; idx < 2048; idx += 256) {
            int mm = idx >> 6, k4 = idx & 63;
            *(float4*)&KVs[mm][k4*4] = *(const float4*)(outs + ((size_t)b*1024 + m0 + mm)*256 + k4*4);
        }
        __syncthreads();
        {
            float sc0 = rowScaleL[2*rp], sc1 = rowScaleL[2*rp+1];
            #pragma unroll
            for (int j = 0; j < 8; ++j) { accA[j] *= sc0; accB[j] *= sc1; }
            int c0 = cg << 3;
            #pragma unroll 4
            for (int mm = 0; mm < 32; ++mm) {
                float p0 = sS[2*rp][mm], p1 = sS[2*rp+1][mm];
                float4 vA = *(const float4*)&KVs[mm][c0];
                float4 vB = *(const float4*)&KVs[mm][c0+4];
                accA[0] += p0*vA.x; accA[1] += p0*vA.y; accA[2] += p0*vA.z; accA[3] += p0*vA.w;
                accA[4] += p0*vB.x; accA[5] += p0*vB.y; accA[6] += p0*vB.z; accA[7] += p0*vB.w;
                accB[0] += p1*vA.x; accB[1] += p1*vA.y; accB[2] += p1*vA.z; accB[3] += p1*vA.w;
                accB[4] += p1*vB.x; accB[5] += p1*vB.y; accB[6] += p1*vB.z; accB[7] += p1*vB.w;
            }
        }
    }
    __syncthreads();
    int c0 = cg << 3;
    {
        int l = l0 + 2*rp;
        float inv = (l == 0) ? 0.f : 1.f/rowLL[2*rp];
        float4* cp = (float4*)(ctx + ((size_t)b*1024 + l)*256 + c0);
        cp[0] = make_float4(accA[0]*inv, accA[1]*inv, accA[2]*inv, accA[3]*inv);
        cp[1] = make_float4(accA[4]*inv, accA[5]*inv, accA[6]*inv, accA[7]*inv);
    }
    {
        int l = l0 + 2*rp + 1;
        float inv = 1.f/rowLL[2*rp+1];
        float4* cp = (float4*)(ctx + ((size_t)b*1024 + l)*256 + c0);
        cp[0] = make_float4(accB[0]*inv, accB[1]*inv, accB[2]*inv, accB[3]*inv);
        cp[1] = make_float4(accB[4]*inv, accB[5]*inv, accB[6]*inv, accB[7]*inv);
    }
}

// ---------------- final: logits + outputs ----------------
__global__ __launch_bounds__(256) void k_final(
    const float* __restrict__ h2v, const float* __restrict__ w2, const float* __restrict__ b2,
    const float* __restrict__ mask, float* __restrict__ out)
{
    int i = blockIdx.x*256 + threadIdx.x;   // < 32768
    const float4* h4 = (const float4*)(h2v + (size_t)i*256);
    const float4* w4 = (const float4*)w2;
    float a0=0,a1=0,a2=0,a3=0;
    #pragma unroll 8
    for (int k = 0; k < 64; ++k) {
        float4 h = h4[k], w = w4[k];
        a0 += h.x*w.x; a1 += h.y*w.y; a2 += h.z*w.z; a3 += h.w*w.w;
    }
    float lg = a0+a1+a2+a3 + b2[0];
    float p = sigm(lg);
    out[2*i]     = 1.0f - p;
    out[2*i + 1] = p;
    out[65536  + i] = (lg > 0.f) ? 1.0f : ((lg < 0.f) ? -1.0f : 0.0f);
    out[98304  + i] = mask[i];
    out[131072 + i] = lg;
}

extern "C" void kernel_launch(void* const* d_in, const int* in_sizes, int n_in,
                              void* d_out, int out_size, void* d_ws, size_t ws_size,
                              hipStream_t stream)
{
    const float* ne      = (const float*)d_in[0];
    const float* mask    = (const float*)d_in[1];
    const int*   trg     = (const int*)  d_in[2];
    const float* se_w0   = (const float*)d_in[3];
    const float* se_b0   = (const float*)d_in[4];
    const float* se_w1   = (const float*)d_in[5];
    const float* se_b1   = (const float*)d_in[6];
    const float* se_w2   = (const float*)d_in[7];
    const float* se_b2   = (const float*)d_in[8];
    const float* w_ih0   = (const float*)d_in[9];
    const float* w_hh0   = (const float*)d_in[10];
    const float* b_ih0   = (const float*)d_in[11];
    const float* b_hh0   = (const float*)d_in[12];
    const float* w_ih1   = (const float*)d_in[13];
    const float* w_hh1   = (const float*)d_in[14];
    const float* b_ih1   = (const float*)d_in[15];
    const float* b_hh1   = (const float*)d_in[16];
    const float* attn_w1 = (const float*)d_in[17];
    const float* attn_b1 = (const float*)d_in[18];
    const float* comb_w  = (const float*)d_in[19];
    const float* comb_b  = (const float*)d_in[20];
    const float* dec_w0  = (const float*)d_in[21];
    const float* dec_b0  = (const float*)d_in[22];
    const float* dec_w1  = (const float*)d_in[23];
    const float* dec_b1  = (const float*)d_in[24];
    const float* dec_w2  = (const float*)d_in[25];
    const float* dec_b2  = (const float*)d_in[26];

    float* W    = (float*)d_ws;
    float* sh   = W;                    // 8192
    float* o0   = W + 8192;             // [L,B,D] 8388608
    float* xp1  = W + 8396800;          // [L,B,G] 25165824
    float* outs = W + 33562624;         // [B,L,D] 8388608  (total 41951232 floats = 160 MB)
    float* modif = o0;                  // reuse (o0 dead after xp1 GEMM)
    float* ctx  = xp1;                  // reuse (xp1 dead after scan1)
    float* dec  = xp1 + 8388608;
    float* h1   = xp1 + 16777216;
    float* h2b  = o0;                   // reuse (modif dead after attention)
    float* out  = (float*)d_out;

    k_start_embed<<<32, 256, 0, stream>>>(ne, se_w0, se_b0, se_w1, se_b1, se_w2, se_b2, sh);
    k_gru3<0><<<32, 512, 0, stream>>>(w_hh0, b_hh0, w_ih0, b_ih0, nullptr, trg, sh, o0);
    k_gemm_mfma<<<1536, 256, 0, stream>>>(o0, w_ih1, b_ih1, xp1, NROWS, 768, 256, 0, 0, nullptr, nullptr);
    k_gru3<1><<<32, 512, 0, stream>>>(w_hh1, b_hh1, nullptr, nullptr, xp1, trg, sh, outs);
    k_gemm_mfma<<<512, 256, 0, stream>>>(outs, attn_w1, attn_b1, modif, NROWS, 256, 256, 0, 0, nullptr, nullptr);
    { dim3 ag(64, 32); k_attn<<<ag, 256, 0, stream>>>(outs, modif, ctx); }
    k_gemm_mfma<<<512, 256, 0, stream>>>(ctx, comb_w, comb_b, dec, NROWS, 256, 768, 2, 3, outs, sh);
    k_gemm_mfma<<<512, 256, 0, stream>>>(dec, dec_w0, dec_b0, h1, NROWS, 256, 256, 1, 0, nullptr, nullptr);
    k_gemm_mfma<<<512, 256, 0, stream>>>(h1, dec_w1, dec_b1, h2b, NROWS, 256, 256, 1, 0, nullptr, nullptr);
    k_final<<<128, 256, 0, stream>>>(h2b, dec_w2, dec_b2, mask, out);
}

// Round 16
// 2976.935 us; speedup vs baseline: 1.2923x; 1.1538x over previous
//
#include <hip/hip_runtime.h>
#include <math.h>

// B=32, L=1024, D=256, G=768
#define NROWS 32768  // B*L

typedef float v4 __attribute__((ext_vector_type(4)));
typedef _Float16 h2 __attribute__((ext_vector_type(2)));
typedef _Float16 f16x8 __attribute__((ext_vector_type(8)));
typedef float f32x4 __attribute__((ext_vector_type(4)));

__device__ __forceinline__ float geluf(float x){ return 0.5f*x*(1.0f+erff(x*0.70710678118654752f)); }

// ---- fast transcendentals: native v_exp_f32 (exp2) + v_rcp_f32 ----
__device__ __forceinline__ float fexp2(float x){
#if __has_builtin(__builtin_amdgcn_exp2f)
    return __builtin_amdgcn_exp2f(x);
#else
    return exp2f(x);
#endif
}
__device__ __forceinline__ float frcp(float x){
#if __has_builtin(__builtin_amdgcn_rcpf)
    return __builtin_amdgcn_rcpf(x);
#else
    return 1.0f/x;
#endif
}
#define LOG2E 1.44269504088896f
__device__ __forceinline__ float fexp(float x){ return fexp2(x*LOG2E); }
__device__ __forceinline__ float sigm(float x){ return frcp(1.0f + fexp2(-LOG2E*x)); }
__device__ __forceinline__ float ftanh(float x){ return 1.0f - 2.0f*frcp(fexp2(2.0f*LOG2E*x) + 1.0f); }

__device__ __forceinline__ float dot2(h2 a, h2 b, float c){
#if __has_builtin(__builtin_amdgcn_fdot2)
    return __builtin_amdgcn_fdot2(a, b, c, false);
#else
    return c + (float)a.x*(float)b.x + (float)a.y*(float)b.y;
#endif
}
__device__ __forceinline__ h2 cvt2(float2 a){ return h2{(_Float16)a.x, (_Float16)a.y}; }

// barrier that does NOT drain vmcnt: LDS visibility only (R12-passing form).
__device__ __forceinline__ void wg_barrier(){
    asm volatile("s_waitcnt lgkmcnt(0)" ::: "memory");
    __builtin_amdgcn_s_barrier();
    __builtin_amdgcn_sched_barrier(0);
}

// ---------------- start embed: sh[b,d] ----------------
__global__ __launch_bounds__(256) void k_start_embed(
    const float* __restrict__ ne, const float* __restrict__ w0, const float* __restrict__ b0,
    const float* __restrict__ w1, const float* __restrict__ b1,
    const float* __restrict__ w2, const float* __restrict__ b2,
    float* __restrict__ sh)
{
    __shared__ __align__(16) float encL[1024];
    __shared__ __align__(16) float g1[256];
    __shared__ __align__(16) float g2[256];
    int b = blockIdx.x, t = threadIdx.x;
    for (int i = t; i < 1024; i += 256) encL[i] = ne[b*1024 + i];
    __syncthreads();
    const float4* wr = (const float4*)(w0 + (size_t)t*1024);
    const float4* e4 = (const float4*)encL;
    float a0=0,a1=0,a2=0,a3=0;
    #pragma unroll 8
    for (int k = 0; k < 256; ++k){ float4 w = wr[k], e = e4[k];
        a0 += w.x*e.x; a1 += w.y*e.y; a2 += w.z*e.z; a3 += w.w*e.w; }
    float t1 = a0+a1+a2+a3 + b0[t];
    float res = t1;
    g1[t] = geluf(t1);
    __syncthreads();
    const float4* w1r = (const float4*)(w1 + (size_t)t*256);
    const float4* g14 = (const float4*)g1;
    a0=a1=a2=a3=0.f;
    #pragma unroll 8
    for (int k = 0; k < 64; ++k){ float4 w = w1r[k], e = g14[k];
        a0 += w.x*e.x; a1 += w.y*e.y; a2 += w.z*e.z; a3 += w.w*e.w; }
    g2[t] = geluf(a0+a1+a2+a3 + b1[t]);
    __syncthreads();
    const float4* w2r = (const float4*)(w2 + (size_t)t*256);
    const float4* g24 = (const float4*)g2;
    a0=a1=a2=a3=0.f;
    #pragma unroll 8
    for (int k = 0; k < 64; ++k){ float4 w = w2r[k], e = g24[k];
        a0 += w.x*e.x; a1 += w.y*e.y; a2 += w.z*e.z; a3 += w.w*e.w; }
    sh[b*256 + t] = a0+a1+a2+a3 + b2[t] + res;
}

// permuted f16 index within an hbuf row for hidden dim:
// dim = (hi:2)(mid:3)(lo:3) -> idx = mid*32 + hi*8 + lo  (bijective).
__device__ __forceinline__ int hperm(int dim){
    return ((dim >> 3) & 7)*32 + ((dim >> 6) << 3) + (dim & 7);
}

// ---------------- GRU scan v12 (exact R12-passing version) ----------------
template<int LAYER>
__global__ __launch_bounds__(512) void k_gru3(
    const float* __restrict__ w_hh, const float* __restrict__ b_hh,
    const float* __restrict__ w_ih0, const float* __restrict__ b_ih0,
    const float* __restrict__ xp1,
    const int*   __restrict__ trg,
    const float* __restrict__ sh,
    float* __restrict__ out)
{
    __shared__ __align__(16) float4 wNs[8192];      // 128KB: [kk 0..15][t 0..511]
    __shared__ __align__(16) _Float16 hbuf[2][256];
    __shared__ __align__(16) float bitL[1024];
    int b = blockIdx.x, t = threadIdx.x;
    int d = t >> 1, half = t & 1;

    if (LAYER == 0) {
        #pragma unroll
        for (int i = 0; i < 2; ++i) {
            int idx = t + i*512;
            bitL[idx] = (idx == 0) ? 1.0f : (float)trg[b*1024 + idx - 1];
        }
    }

    // --- wN K-half of row d -> LDS (f16 packed), once; linear, conflict-free ---
    {
        const float2* src = (const float2*)(w_hh + (size_t)(512 + d)*256 + half*128);
        #pragma unroll
        for (int kk = 0; kk < 16; ++kk) {
            h2 p0 = cvt2(src[kk*4+0]), p1 = cvt2(src[kk*4+1]);
            h2 p2 = cvt2(src[kk*4+2]), p3 = cvt2(src[kk*4+3]);
            float4 v;
            v.x = __builtin_bit_cast(float, p0); v.y = __builtin_bit_cast(float, p1);
            v.z = __builtin_bit_cast(float, p2); v.w = __builtin_bit_cast(float, p3);
            wNs[kk*512 + t] = v;
        }
    }
    // --- wR, wZ K-halves -> registers (f16 packed) ---
    h2 wR[64], wZ[64];
    {
        const float2* wr = (const float2*)(w_hh + (size_t)d*256       + half*128);
        const float2* wz = (const float2*)(w_hh + (size_t)(d+256)*256 + half*128);
        #pragma unroll
        for (int k = 0; k < 64; ++k) { wR[k] = cvt2(wr[k]); wZ[k] = cvt2(wz[k]); }
    }
    float bhr = b_hh[d], bhz = b_hh[256 + d], bhn = b_hh[512 + d];
    float wir=0.f, wiz=0.f, win=0.f, bir=0.f, biz=0.f, bin=0.f;
    if (LAYER == 0) {
        wir = w_ih0[d]; wiz = w_ih0[256 + d]; win = w_ih0[512 + d];
        bir = b_ih0[d]; biz = b_ih0[256 + d]; bin = b_ih0[512 + d];
    }

    float hreg = sh[b*256 + d];
    if (half == 0) hbuf[0][hperm(d)] = (_Float16)hreg;

    float xr = 0.f, xz = 0.f, xn = 0.f;
    if (LAYER == 1) {
        size_t base = (size_t)b*768;
        xr = xp1[base + d]; xz = xp1[base + 256 + d]; xn = xp1[base + 512 + d];
    }
    __syncthreads();

    for (int l = 0; l < 1024; ++l) {
        const float4* hb4 = (const float4*)(&hbuf[l & 1][0]);
        float ar = 0.f, az = 0.f, an = 0.f;
        #pragma unroll
        for (int kk = 0; kk < 16; ++kk) {
            float4 hv = hb4[(kk & 7)*4 + half*2 + (kk >> 3)];  // wave 2-addr broadcast
            float4 wv = wNs[kk*512 + t];                       // conflict-free private
            h2 h0 = __builtin_bit_cast(h2, hv.x);
            h2 h1 = __builtin_bit_cast(h2, hv.y);
            h2 hc = __builtin_bit_cast(h2, hv.z);
            h2 h3 = __builtin_bit_cast(h2, hv.w);
            ar = dot2(wR[4*kk+0], h0, ar); ar = dot2(wR[4*kk+1], h1, ar);
            ar = dot2(wR[4*kk+2], hc, ar); ar = dot2(wR[4*kk+3], h3, ar);
            az = dot2(wZ[4*kk+0], h0, az); az = dot2(wZ[4*kk+1], h1, az);
            az = dot2(wZ[4*kk+2], hc, az); az = dot2(wZ[4*kk+3], h3, az);
            an = dot2(__builtin_bit_cast(h2, wv.x), h0, an);
            an = dot2(__builtin_bit_cast(h2, wv.y), h1, an);
            an = dot2(__builtin_bit_cast(h2, wv.z), hc, an);
            an = dot2(__builtin_bit_cast(h2, wv.w), h3, an);
        }
        ar += __shfl_xor(ar, 1);
        az += __shfl_xor(az, 1);
        an += __shfl_xor(an, 1);
        if (LAYER == 0) {
            float bit = bitL[l];
            xr = bir + bit*wir; xz = biz + bit*wiz; xn = bin + bit*win;
        }
        float r = sigm(xr + ar + bhr);
        float z = sigm(xz + az + bhz);
        float n = ftanh(xn + r*(an + bhn));
        hreg = (1.0f - z)*n + z*hreg;
        if (half == 0) {
            hbuf[(l + 1) & 1][hperm(d)] = (_Float16)hreg;
        } else {
            size_t oidx = (LAYER == 0) ? (((size_t)l*32 + b)*256 + d)
                                       : (((size_t)b*1024 + l)*256 + d);
            out[oidx] = hreg;
        }
        if (LAYER == 1) {
            int ln = (l < 1023) ? (l + 1) : 1023;
            size_t base = ((size_t)ln*32 + b)*768;
            xr = xp1[base + d]; xz = xp1[base + 256 + d]; xn = xp1[base + 512 + d];
        }
        wg_barrier();
    }
}

// ---------------- f16 MFMA GEMM (as R9, verified) ----------------
__global__ __launch_bounds__(256, 3) void k_gemm_mfma(
    const float* __restrict__ A, const float* __restrict__ B,
    const float* __restrict__ bias, float* __restrict__ C,
    int M, int N, int K, int act, int aMode,
    const float* __restrict__ A1, const float* __restrict__ A2)
{
    __shared__ __align__(16) _Float16 As[128][40];
    __shared__ __align__(16) _Float16 Bs[128][40];
    int nbn = N >> 7;
    int bx = blockIdx.x % nbn, by = blockIdx.x / nbn;
    int m0 = by << 7, n0 = bx << 7;
    int t = threadIdx.x;
    int w = t >> 6, l = t & 63;
    int wm = w >> 1, wn = w & 1;
    int lc = l & 15, lg = l >> 4;
    f32x4 acc[4][4] = {};
    for (int kt = 0; kt < K; kt += 32) {
        __syncthreads();
        #pragma unroll
        for (int p = 0; p < 4; ++p) {
            int slot = t + p*256;            // 1024 slots: (m, kc)
            int m = slot >> 3, kc = slot & 7;
            int gk = kt + kc*4;
            float4 va;
            if (aMode == 0) {
                va = *(const float4*)(A + (size_t)(m0+m)*K + gk);
            } else {
                int part = gk >> 8, kk = gk & 255;
                const float* P = (part == 0) ? A : ((part == 1) ? A1 : A2);
                int row = (part == 2) ? ((m0+m) >> 10) : (m0+m);
                va = *(const float4*)(P + (size_t)row*256 + kk);
            }
            h2 pa; pa[0] = (_Float16)va.x; pa[1] = (_Float16)va.y;
            h2 pb; pb[0] = (_Float16)va.z; pb[1] = (_Float16)va.w;
            *(float2*)(&As[m][kc*4]) = make_float2(__builtin_bit_cast(float, pa),
                                                   __builtin_bit_cast(float, pb));
            float4 vb = *(const float4*)(B + (size_t)(n0+m)*K + gk);
            h2 qa; qa[0] = (_Float16)vb.x; qa[1] = (_Float16)vb.y;
            h2 qb; qb[0] = (_Float16)vb.z; qb[1] = (_Float16)vb.w;
            *(float2*)(&Bs[m][kc*4]) = make_float2(__builtin_bit_cast(float, qa),
                                                   __builtin_bit_cast(float, qb));
        }
        __syncthreads();
        f16x8 af[4], bf[4];
        #pragma unroll
        for (int mt = 0; mt < 4; ++mt)
            af[mt] = *(const f16x8*)(&As[wm*64 + mt*16 + lc][lg*8]);
        #pragma unroll
        for (int nt = 0; nt < 4; ++nt)
            bf[nt] = *(const f16x8*)(&Bs[wn*64 + nt*16 + lc][lg*8]);
        #pragma unroll
        for (int mt = 0; mt < 4; ++mt)
            #pragma unroll
            for (int nt = 0; nt < 4; ++nt)
                acc[mt][nt] = __builtin_amdgcn_mfma_f32_16x16x32_f16(af[mt], bf[nt], acc[mt][nt], 0, 0, 0);
    }
    #pragma unroll
    for (int nt = 0; nt < 4; ++nt) {
        int col = n0 + wn*64 + nt*16 + lc;
        float bv = bias[col];
        #pragma unroll
        for (int mt = 0; mt < 4; ++mt) {
            int rbase = m0 + wm*64 + mt*16 + lg*4;
            #pragma unroll
            for (int r = 0; r < 4; ++r) {
                float v = acc[mt][nt][r] + bv;
                if (act == 1) v = geluf(v);
                else if (act == 2) v = ftanh(v);
                C[(size_t)(rbase + r)*N + col] = v;
            }
        }
    }
}

// ---------------- MFMA flash attention v4: full hi/lo + FIXED GRID ----------------
// R13-R15 all failed identically (output 1 absmax exactly 2.0) across three
// precision levels -> structural, not numeric. Found it: grid was (8,32) but
// the kernel covers 64 Q-rows/block -> rows 512..1023 of ctx never written
// (stale xp1 garbage, since ctx aliases xp1). Fix: grid (16,32). Kernel body
// byte-identical to R15 (full hi/lo QK and PV; precision proven-safe level).
__global__ __launch_bounds__(256) void k_attn_mfma(
    const float* __restrict__ outs, const float* __restrict__ modif, float* __restrict__ ctx)
{
    __shared__ __align__(16) _Float16 Qsh[64][264];
    __shared__ __align__(16) _Float16 Qsl[64][264];
    __shared__ __align__(16) _Float16 Ksh[32][264];
    __shared__ __align__(16) _Float16 Ksl[32][264];
    __shared__ __align__(16) _Float16 Vth[256][40];
    __shared__ __align__(16) _Float16 Vtl[256][40];
    __shared__ __align__(16) _Float16 sPh[4][16][40];
    __shared__ __align__(16) _Float16 sPl[4][16][40];
    int b = blockIdx.y, bx = blockIdx.x, l0 = bx << 6, t = threadIdx.x;
    int w = t >> 6, l = t & 63;
    int lc = l & 15, lg = l >> 4;

    // stage Q hi/lo (64 rows, f32 -> f16 + residual)
    #pragma unroll
    for (int p = 0; p < 16; ++p) {
        int i = p*256 + t;
        int row = i >> 6, c4 = i & 63;
        float4 v = *(const float4*)(outs + ((size_t)b*1024 + l0 + row)*256 + c4*4);
        _Float16 hx = (_Float16)v.x, hy = (_Float16)v.y, hz = (_Float16)v.z, hw = (_Float16)v.w;
        h2 pa; pa[0] = hx; pa[1] = hy;
        h2 pb; pb[0] = hz; pb[1] = hw;
        *(float2*)(&Qsh[row][c4*4]) = make_float2(__builtin_bit_cast(float, pa),
                                                  __builtin_bit_cast(float, pb));
        h2 la; la[0] = (_Float16)(v.x - (float)hx); la[1] = (_Float16)(v.y - (float)hy);
        h2 lb; lb[0] = (_Float16)(v.z - (float)hz); lb[1] = (_Float16)(v.w - (float)hw);
        *(float2*)(&Qsl[row][c4*4]) = make_float2(__builtin_bit_cast(float, la),
                                                  __builtin_bit_cast(float, lb));
    }
    __syncthreads();
    // cache Q A-frags (hi and lo): lane holds Q[w + 4*lc][kf*32 + lg*8 + j]
    f16x8 aqh[8], aql[8];
    #pragma unroll
    for (int kf = 0; kf < 8; ++kf) {
        aqh[kf] = *(const f16x8*)(&Qsh[w + 4*lc][kf*32 + lg*8]);
        aql[kf] = *(const f16x8*)(&Qsl[w + 4*lc][kf*32 + lg*8]);
    }

    f32x4 cacc[16] = {};
    float rowM[4] = {-1e30f, -1e30f, -1e30f, -1e30f};
    float rowL[4] = {0.f, 0.f, 0.f, 0.f};

    int T = 2*bx + 2;
    for (int tt = 0; tt < T; ++tt) {
        int m0 = tt << 5;
        __syncthreads();
        // stage K hi/lo (modif) and V^T hi/lo (outs)
        #pragma unroll
        for (int p = 0; p < 8; ++p) {
            int i = p*256 + t;
            int row = i >> 6, c4 = i & 63;
            float4 kv = *(const float4*)(modif + ((size_t)b*1024 + m0 + row)*256 + c4*4);
            _Float16 hx = (_Float16)kv.x, hy = (_Float16)kv.y, hz = (_Float16)kv.z, hw = (_Float16)kv.w;
            h2 pa; pa[0] = hx; pa[1] = hy;
            h2 pb; pb[0] = hz; pb[1] = hw;
            *(float2*)(&Ksh[row][c4*4]) = make_float2(__builtin_bit_cast(float, pa),
                                                      __builtin_bit_cast(float, pb));
            h2 la; la[0] = (_Float16)(kv.x - (float)hx); la[1] = (_Float16)(kv.y - (float)hy);
            h2 lb; lb[0] = (_Float16)(kv.z - (float)hz); lb[1] = (_Float16)(kv.w - (float)hw);
            *(float2*)(&Ksl[row][c4*4]) = make_float2(__builtin_bit_cast(float, la),
                                                      __builtin_bit_cast(float, lb));
            float4 vv = *(const float4*)(outs + ((size_t)b*1024 + m0 + row)*256 + c4*4);
            _Float16 vx = (_Float16)vv.x, vy = (_Float16)vv.y, vz = (_Float16)vv.z, vw = (_Float16)vv.w;
            Vth[c4*4+0][row] = vx;  Vtl[c4*4+0][row] = (_Float16)(vv.x - (float)vx);
            Vth[c4*4+1][row] = vy;  Vtl[c4*4+1][row] = (_Float16)(vv.y - (float)vy);
            Vth[c4*4+2][row] = vz;  Vtl[c4*4+2][row] = (_Float16)(vv.z - (float)vz);
            Vth[c4*4+3][row] = vw;  Vtl[c4*4+3][row] = (_Float16)(vv.w - (float)vw);
        }
        __syncthreads();
        // QK: S[16,32] = Q . K^T, hi/lo split (3 MFMAs per B-frag)
        f32x4 s0 = {0.f,0.f,0.f,0.f}, s1 = {0.f,0.f,0.f,0.f};
        #pragma unroll
        for (int kf = 0; kf < 8; ++kf) {
            f16x8 b0h = *(const f16x8*)(&Ksh[lc][kf*32 + lg*8]);
            f16x8 b0l = *(const f16x8*)(&Ksl[lc][kf*32 + lg*8]);
            f16x8 b1h = *(const f16x8*)(&Ksh[16 + lc][kf*32 + lg*8]);
            f16x8 b1l = *(const f16x8*)(&Ksl[16 + lc][kf*32 + lg*8]);
            s0 = __builtin_amdgcn_mfma_f32_16x16x32_f16(aqh[kf], b0h, s0, 0, 0, 0);
            s0 = __builtin_amdgcn_mfma_f32_16x16x32_f16(aqh[kf], b0l, s0, 0, 0, 0);
            s0 = __builtin_amdgcn_mfma_f32_16x16x32_f16(aql[kf], b0h, s0, 0, 0, 0);
            s1 = __builtin_amdgcn_mfma_f32_16x16x32_f16(aqh[kf], b1h, s1, 0, 0, 0);
            s1 = __builtin_amdgcn_mfma_f32_16x16x32_f16(aqh[kf], b1l, s1, 0, 0, 0);
            s1 = __builtin_amdgcn_mfma_f32_16x16x32_f16(aql[kf], b1h, s1, 0, 0, 0);
        }
        // mask + online softmax (in C-frag registers); P stored hi/lo
        #pragma unroll
        for (int r = 0; r < 4; ++r) {
            int m = lg*4 + r;
            int grow = l0 + w + 4*m;
            float v0 = s0[r], v1 = s1[r];
            if (m0 + lc      >= grow) v0 = -1e30f;
            if (m0 + 16 + lc >= grow) v1 = -1e30f;
            float mx = fmaxf(v0, v1);
            mx = fmaxf(mx, __shfl_xor(mx, 1));
            mx = fmaxf(mx, __shfl_xor(mx, 2));
            mx = fmaxf(mx, __shfl_xor(mx, 4));
            mx = fmaxf(mx, __shfl_xor(mx, 8));
            float nm = fmaxf(rowM[r], mx);
            float sc, p0, p1;
            if (nm < -1e29f) { sc = 1.f; p0 = 0.f; p1 = 0.f; }
            else { sc = fexp(rowM[r] - nm); p0 = fexp(v0 - nm); p1 = fexp(v1 - nm); }
            rowM[r] = nm;
            float ts = p0 + p1;
            ts += __shfl_xor(ts, 1);
            ts += __shfl_xor(ts, 2);
            ts += __shfl_xor(ts, 4);
            ts += __shfl_xor(ts, 8);
            rowL[r] = rowL[r]*sc + ts;
            _Float16 p0h = (_Float16)p0, p1h = (_Float16)p1;
            sPh[w][m][lc]      = p0h;  sPl[w][m][lc]      = (_Float16)(p0 - (float)p0h);
            sPh[w][m][16 + lc] = p1h;  sPl[w][m][16 + lc] = (_Float16)(p1 - (float)p1h);
            #pragma unroll
            for (int nt = 0; nt < 16; ++nt) cacc[nt][r] *= sc;
        }
        asm volatile("s_waitcnt lgkmcnt(0)" ::: "memory");
        __builtin_amdgcn_sched_barrier(0);
        // P A-frags (wave-private; rows all written by this wave)
        f16x8 pah = *(const f16x8*)(&sPh[w][lc][lg*8]);
        f16x8 pal = *(const f16x8*)(&sPl[w][lc][lg*8]);
        // PV: ctx[16,256] += P[16,32] . V[32,256], hi/lo split
        #pragma unroll
        for (int nt = 0; nt < 16; ++nt) {
            f16x8 bvh = *(const f16x8*)(&Vth[nt*16 + lc][lg*8]);
            f16x8 bvl = *(const f16x8*)(&Vtl[nt*16 + lc][lg*8]);
            cacc[nt] = __builtin_amdgcn_mfma_f32_16x16x32_f16(pah, bvh, cacc[nt], 0, 0, 0);
            cacc[nt] = __builtin_amdgcn_mfma_f32_16x16x32_f16(pah, bvl, cacc[nt], 0, 0, 0);
            cacc[nt] = __builtin_amdgcn_mfma_f32_16x16x32_f16(pal, bvh, cacc[nt], 0, 0, 0);
        }
    }
    // write ctx (exact IEEE divide, as the R12-passing kernel)
    #pragma unroll
    for (int r = 0; r < 4; ++r) {
        int grow = l0 + w + 4*(lg*4 + r);
        float inv = (grow == 0) ? 0.f : 1.f/rowL[r];
        #pragma unroll
        for (int nt = 0; nt < 16; ++nt)
            ctx[((size_t)b*1024 + grow)*256 + nt*16 + lc] = cacc[nt][r]*inv;
    }
}

// ---------------- final: logits + outputs ----------------
__global__ __launch_bounds__(256) void k_final(
    const float* __restrict__ h2v, const float* __restrict__ w2, const float* __restrict__ b2,
    const float* __restrict__ mask, float* __restrict__ out)
{
    int i = blockIdx.x*256 + threadIdx.x;   // < 32768
    const float4* h4 = (const float4*)(h2v + (size_t)i*256);
    const float4* w4 = (const float4*)w2;
    float a0=0,a1=0,a2=0,a3=0;
    #pragma unroll 8
    for (int k = 0; k < 64; ++k) {
        float4 h = h4[k], w = w4[k];
        a0 += h.x*w.x; a1 += h.y*w.y; a2 += h.z*w.z; a3 += h.w*w.w;
    }
    float lg = a0+a1+a2+a3 + b2[0];
    float p = sigm(lg);
    out[2*i]     = 1.0f - p;
    out[2*i + 1] = p;
    out[65536  + i] = (lg > 0.f) ? 1.0f : ((lg < 0.f) ? -1.0f : 0.0f);
    out[98304  + i] = mask[i];
    out[131072 + i] = lg;
}

extern "C" void kernel_launch(void* const* d_in, const int* in_sizes, int n_in,
                              void* d_out, int out_size, void* d_ws, size_t ws_size,
                              hipStream_t stream)
{
    const float* ne      = (const float*)d_in[0];
    const float* mask    = (const float*)d_in[1];
    const int*   trg     = (const int*)  d_in[2];
    const float* se_w0   = (const float*)d_in[3];
    const float* se_b0   = (const float*)d_in[4];
    const float* se_w1   = (const float*)d_in[5];
    const float* se_b1   = (const float*)d_in[6];
    const float* se_w2   = (const float*)d_in[7];
    const float* se_b2   = (const float*)d_in[8];
    const float* w_ih0   = (const float*)d_in[9];
    const float* w_hh0   = (const float*)d_in[10];
    const float* b_ih0   = (const float*)d_in[11];
    const float* b_hh0   = (const float*)d_in[12];
    const float* w_ih1   = (const float*)d_in[13];
    const float* w_hh1   = (const float*)d_in[14];
    const float* b_ih1   = (const float*)d_in[15];
    const float* b_hh1   = (const float*)d_in[16];
    const float* attn_w1 = (const float*)d_in[17];
    const float* attn_b1 = (const float*)d_in[18];
    const float* comb_w  = (const float*)d_in[19];
    const float* comb_b  = (const float*)d_in[20];
    const float* dec_w0  = (const float*)d_in[21];
    const float* dec_b0  = (const float*)d_in[22];
    const float* dec_w1  = (const float*)d_in[23];
    const float* dec_b1  = (const float*)d_in[24];
    const float* dec_w2  = (const float*)d_in[25];
    const float* dec_b2  = (const float*)d_in[26];

    float* W    = (float*)d_ws;
    float* sh   = W;                    // 8192
    float* o0   = W + 8192;             // [L,B,D] 8388608
    float* xp1  = W + 8396800;          // [L,B,G] 25165824
    float* outs = W + 33562624;         // [B,L,D] 8388608  (total 41951232 floats = 160 MB)
    float* modif = o0;                  // reuse (o0 dead after xp1 GEMM)
    float* ctx  = xp1;                  // reuse (xp1 dead after scan1)
    float* dec  = xp1 + 8388608;
    float* h1   = xp1 + 16777216;
    float* h2b  = o0;                   // reuse (modif dead after attention)
    float* out  = (float*)d_out;

    k_start_embed<<<32, 256, 0, stream>>>(ne, se_w0, se_b0, se_w1, se_b1, se_w2, se_b2, sh);
    k_gru3<0><<<32, 512, 0, stream>>>(w_hh0, b_hh0, w_ih0, b_ih0, nullptr, trg, sh, o0);
    k_gemm_mfma<<<1536, 256, 0, stream>>>(o0, w_ih1, b_ih1, xp1, NROWS, 768, 256, 0, 0, nullptr, nullptr);
    k_gru3<1><<<32, 512, 0, stream>>>(w_hh1, b_hh1, nullptr, nullptr, xp1, trg, sh, outs);
    k_gemm_mfma<<<512, 256, 0, stream>>>(outs, attn_w1, attn_b1, modif, NROWS, 256, 256, 0, 0, nullptr, nullptr);
    { dim3 ag(16, 32); k_attn_mfma<<<ag, 256, 0, stream>>>(outs, modif, ctx); }
    k_gemm_mfma<<<512, 256, 0, stream>>>(ctx, comb_w, comb_b, dec, NROWS, 256, 768, 2, 3, outs, sh);
    k_gemm_mfma<<<512, 256, 0, stream>>>(dec, dec_w0, dec_b0, h1, NROWS, 256, 256, 1, 0, nullptr, nullptr);
    k_gemm_mfma<<<512, 256, 0, stream>>>(h1, dec_w1, dec_b1, h2b, NROWS, 256, 256, 1, 0, nullptr, nullptr);
    k_final<<<128, 256, 0, stream>>>(h2b, dec_w2, dec_b2, mask, out);
}